// Round 15
// baseline (1079.923 us; speedup 1.0000x reference)
//
#include <hip/hip_runtime.h>

#define Bb 64
#define Tt 2048
#define Ii 64
#define Hh 128
#define Gg 384   // 3*H
#define Oo 64

typedef _Float16 f16;
typedef _Float16 half8 __attribute__((ext_vector_type(8)));
typedef __fp16 fp16v2 __attribute__((ext_vector_type(2)));   // cvt_pkrtz native type
typedef float f32x4 __attribute__((ext_vector_type(4)));
typedef unsigned int u32;

// ---------------- Fully-fused GRU: x-proj + recurrence + out-proj, ONE kernel.
// 16 blocks x 512 threads; 4 batches/block; batch b in A-row 4b (C row 4b =
// (hi=b, reg 0) -> lane (hi,lo) owns (b=bb0+hi, j=jj)).
// KEY CHANGE vs R14: step t+1's x-MFMAs run in step t's SHADOW (pre-barrier,
// reading x(t+1) from the opposite-parity LDS buffer, which was written at
// step t-1 and synced by t-1's barrier). Their f32x4 accumulators carry across
// the barrier in registers (two sets, alternated by the 2-step unroll). The
// post-barrier critical section is now only: 4 h ds_reads -> 12 h-MFMAs
// (2+2 chains) -> gate eval -> pack/ds_write -> barrier.
// x buffering: x(t') lives in x-region of hsm[(t'-1)&1]; step t writes x(t+2)
// to hsm[WP^1], reads x(t+1) from hsm[WP]. VN = raw x(t+3) loaded at top.
__global__ __launch_bounds__(512, 2) void gru_mfma(
    const float* __restrict__ W_hh, const float* __restrict__ b_hh,
    const float* __restrict__ W_ih, const float* __restrict__ b_ih,
    const float* __restrict__ W_out, const float* __restrict__ b_out,
    const float* __restrict__ inputs, float* __restrict__ out,
    float* __restrict__ latents)
{
    __shared__ __align__(16) unsigned char hsm[2][1536];
    // bytes 0..1023: h region [b][j] f16 (b-parity XOR); 1024..1535: x region

    const int tid = threadIdx.x;
    const int w   = tid >> 6;
    const int l   = tid & 63;
    const int lo  = l & 15;
    const int hi  = l >> 4;
    const int jj  = w * 16 + lo;      // this lane's hidden column
    const int bb0 = blockIdx.x * 4;   // 4 batches per block

    // Gate B fragments: lane lo -> col jj, hi -> k-chunk of 8.
    half8 Bf[3][6];
#pragma unroll
    for (int gt = 0; gt < 3; ++gt) {
#pragma unroll
        for (int ks = 0; ks < 4; ++ks) {
            const float* wp = W_hh + (size_t)(gt * 128 + jj) * 128 + ks * 32 + hi * 8;
            half8 hv;
#pragma unroll
            for (int q = 0; q < 8; ++q) hv[q] = (f16)wp[q];
            Bf[gt][ks] = hv;
        }
#pragma unroll
        for (int ks = 4; ks < 6; ++ks) {
            const float* wp = W_ih + (size_t)(gt * 128 + jj) * 64 + (ks - 4) * 32 + hi * 8;
            half8 hv;
#pragma unroll
            for (int q = 0; q < 8; ++q) hv[q] = (f16)wp[q];
            Bf[gt][ks] = hv;
        }
    }
#pragma unroll
    for (int gt = 0; gt < 3; ++gt)
#pragma unroll
        for (int ks = 0; ks < 6; ++ks)
            asm volatile("" : "+v"(Bf[gt][ks]));

    // Out-proj B fragments (waves 0-3 only): col = jj (<64), k-chunk = hi*8.
    half8 Bw[4];
    float bo = 0.f;
    if (w < 4) {
#pragma unroll
        for (int ks = 0; ks < 4; ++ks) {
            const float* wp = W_out + (size_t)jj * 128 + ks * 32 + hi * 8;
            half8 hv;
#pragma unroll
            for (int q = 0; q < 8; ++q) hv[q] = (f16)wp[q];
            Bw[ks] = hv;
        }
#pragma unroll
        for (int ks = 0; ks < 4; ++ks) asm volatile("" : "+v"(Bw[ks]));
        bo = b_out[jj];
    } else {
        half8 z8 = {};
#pragma unroll
        for (int ks = 0; ks < 4; ++ks) Bw[ks] = z8;
    }

    const float br  = b_hh[jj]       + b_ih[jj];        // r: fully additive
    const float bz  = b_hh[128 + jj] + b_ih[128 + jj];  // z: fully additive
    const float bnh = b_hh[256 + jj];                   // n h-part (inside r*())
    const float bnx = b_ih[256 + jj];                   // n x-part

    float* latp = latents + (size_t)(bb0 + hi) * Tt * 128 + jj;
    float* outp = out     + (size_t)(bb0 + hi) * Tt * 64  + jj;   // w<4 only

    // h-region addresses (R9-validated).
    const int waddr = hi * 256 + ((2 * jj) ^ ((hi & 1) << 6));
    const int rxor  = ((lo >> 2) & 1) << 6;
    const int rb    = (lo << 6);          // h A-read base (b = lo>>2)
    const int xrb   = 1024 + (lo << 5);   // x A-read base

    // x staging (tid < 128): thread covers (b = tid>>5, kpair = tid&31).
    const int xb  = (tid >> 5) & 3;
    const int xkp = tid & 31;
    const float* xsrc = inputs + (size_t)(bb0 + xb) * Tt * 64 + 2 * xkp;
    const int xwaddr  = 1024 + xb * 128 + ((4 * xkp) ^ ((xb & 1) << 6));

    // Prologue: x(0) -> hsm[1], x(1) -> hsm[0]; XW = packed x(2).
    u32 XW = 0;
    float2 VN = {0.f, 0.f};
    if (tid < 128) {
        const float2 v0 = *(const float2*)(xsrc);
        *(fp16v2*)(&hsm[1][xwaddr]) = __builtin_amdgcn_cvt_pkrtz(v0.x, v0.y);
        const float2 v1 = *(const float2*)(xsrc + 64);
        *(fp16v2*)(&hsm[0][xwaddr]) = __builtin_amdgcn_cvt_pkrtz(v1.x, v1.y);
        const float2 v2 = *(const float2*)(xsrc + 128);
        XW = __builtin_bit_cast(u32, __builtin_amdgcn_cvt_pkrtz(v2.x, v2.y));
    }

    float hreg = 0.f, hprev = 0.f;
    half8 A[4];
    half8 z8v = {};
#pragma unroll
    for (int ks = 0; ks < 4; ++ks) A[ks] = z8v;   // h(0) = 0; rows != 4b stay 0

    // Two carried accX sets (A-set serves even t, B-set odd t).
    f32x4 axrA = {0.f, 0.f, 0.f, 0.f}, axzA = {0.f, 0.f, 0.f, 0.f};
    f32x4 axxA = {bnx, bnx, bnx, bnx};
    f32x4 axrB = {0.f, 0.f, 0.f, 0.f}, axzB = {0.f, 0.f, 0.f, 0.f};
    f32x4 axxB = {bnx, bnx, bnx, bnx};

    __syncthreads();
    {   // accX for t=0 from x(0) (in hsm[1])
        half8 Ax0 = z8v, Ax1 = z8v;
        if (!(lo & 3)) {
            Ax0 = *(const half8*)(&hsm[1][xrb + ((hi * 16) ^ rxor)]);
            Ax1 = *(const half8*)(&hsm[1][xrb + ((64 + hi * 16) ^ rxor)]);
        }
        axrA = __builtin_amdgcn_mfma_f32_16x16x32_f16(Ax0, Bf[0][4], axrA, 0, 0, 0);
        axzA = __builtin_amdgcn_mfma_f32_16x16x32_f16(Ax0, Bf[1][4], axzA, 0, 0, 0);
        axxA = __builtin_amdgcn_mfma_f32_16x16x32_f16(Ax0, Bf[2][4], axxA, 0, 0, 0);
        axrA = __builtin_amdgcn_mfma_f32_16x16x32_f16(Ax1, Bf[0][5], axrA, 0, 0, 0);
        axzA = __builtin_amdgcn_mfma_f32_16x16x32_f16(Ax1, Bf[1][5], axzA, 0, 0, 0);
        axxA = __builtin_amdgcn_mfma_f32_16x16x32_f16(Ax1, Bf[2][5], axxA, 0, 0, 0);
    }

// Out-proj for the row currently held in A[ks] (= latents[TR]); waves 0-3.
#define OUTSTEP(TR)                                                              \
    if (w < 4) {                                                                 \
        f32x4 aco0 = {bo, bo, bo, bo};                                           \
        f32x4 aco1 = {0.f, 0.f, 0.f, 0.f};                                       \
        aco0 = __builtin_amdgcn_mfma_f32_16x16x32_f16(A[0], Bw[0], aco0, 0, 0, 0); \
        aco1 = __builtin_amdgcn_mfma_f32_16x16x32_f16(A[1], Bw[1], aco1, 0, 0, 0); \
        aco0 = __builtin_amdgcn_mfma_f32_16x16x32_f16(A[2], Bw[2], aco0, 0, 0, 0); \
        aco1 = __builtin_amdgcn_mfma_f32_16x16x32_f16(A[3], Bw[3], aco1, 0, 0, 0); \
        outp[(size_t)(TR) * 64] = aco0[0] + aco1[0];                             \
    }

#define GSTEP(T, WP, XCr, XCz, XCx, XNr, XNz, XNx)                               \
    {                                                                            \
        const int t_ = (T);                                                      \
        if (tid < 128 && t_ + 3 < Tt)                                            \
            VN = *(const float2*)(xsrc + (size_t)(t_ + 3) * 64);                 \
        /* critical: h-MFMAs (2+2 chains) on A = latents[t-1] */                 \
        f32x4 accr0 = {br, br, br, br},    accr1 = {0.f, 0.f, 0.f, 0.f};         \
        f32x4 accz0 = {bz, bz, bz, bz},    accz1 = {0.f, 0.f, 0.f, 0.f};         \
        f32x4 accn0 = {bnh, bnh, bnh, bnh}, accn1 = {0.f, 0.f, 0.f, 0.f};        \
        accr0 = __builtin_amdgcn_mfma_f32_16x16x32_f16(A[0], Bf[0][0], accr0, 0, 0, 0); \
        accz0 = __builtin_amdgcn_mfma_f32_16x16x32_f16(A[0], Bf[1][0], accz0, 0, 0, 0); \
        accn0 = __builtin_amdgcn_mfma_f32_16x16x32_f16(A[0], Bf[2][0], accn0, 0, 0, 0); \
        accr1 = __builtin_amdgcn_mfma_f32_16x16x32_f16(A[1], Bf[0][1], accr1, 0, 0, 0); \
        accz1 = __builtin_amdgcn_mfma_f32_16x16x32_f16(A[1], Bf[1][1], accz1, 0, 0, 0); \
        accn1 = __builtin_amdgcn_mfma_f32_16x16x32_f16(A[1], Bf[2][1], accn1, 0, 0, 0); \
        accr0 = __builtin_amdgcn_mfma_f32_16x16x32_f16(A[2], Bf[0][2], accr0, 0, 0, 0); \
        accz0 = __builtin_amdgcn_mfma_f32_16x16x32_f16(A[2], Bf[1][2], accz0, 0, 0, 0); \
        accn0 = __builtin_amdgcn_mfma_f32_16x16x32_f16(A[2], Bf[2][2], accn0, 0, 0, 0); \
        accr1 = __builtin_amdgcn_mfma_f32_16x16x32_f16(A[3], Bf[0][3], accr1, 0, 0, 0); \
        accz1 = __builtin_amdgcn_mfma_f32_16x16x32_f16(A[3], Bf[1][3], accz1, 0, 0, 0); \
        accn1 = __builtin_amdgcn_mfma_f32_16x16x32_f16(A[3], Bf[2][3], accn1, 0, 0, 0); \
        if (t_ > 0) latp[(size_t)(t_ - 1) * 128] = hprev;                        \
        /* gate eval: carried accX + fresh h-parts; row 4hi = reg 0 */           \
        const float pr = accr0[0] + accr1[0] + XCr[0];                           \
        const float pz = accz0[0] + accz1[0] + XCz[0];                           \
        const float pn = accn0[0] + accn1[0];                                    \
        const float r = __builtin_amdgcn_rcpf(1.f + __expf(-pr));                \
        const float z = __builtin_amdgcn_rcpf(1.f + __expf(-pz));                \
        const float a = XCx[0] + r * pn;                                         \
        const float n = 1.f - 2.f * __builtin_amdgcn_rcpf(__expf(2.f * a) + 1.f); \
        const float hnew = n + z * (hreg - n);                                   \
        hreg = hnew;                                                             \
        hprev = hnew;                                                            \
        const float other = __shfl_xor(hnew, 1);                                 \
        if (!(l & 1)) {                                                          \
            const fp16v2 pkh = __builtin_amdgcn_cvt_pkrtz(hnew, other);          \
            *(fp16v2*)(&hsm[WP][waddr]) = pkh;                                   \
        }                                                                        \
        if (tid < 128) {                                                         \
            if (t_ + 2 < Tt) *(u32*)(&hsm[(WP) ^ 1][xwaddr]) = XW;               \
            XW = __builtin_bit_cast(u32, __builtin_amdgcn_cvt_pkrtz(VN.x, VN.y)); \
        }                                                                        \
        /* shadow: next step's x-MFMAs (x(t+1) in hsm[WP], synced at t-1) */     \
        if (t_ + 1 < Tt) {                                                       \
            half8 Axn0 = z8v, Axn1 = z8v;                                        \
            if (!(lo & 3)) {                                                     \
                Axn0 = *(const half8*)(&hsm[WP][xrb + ((hi * 16) ^ rxor)]);      \
                Axn1 = *(const half8*)(&hsm[WP][xrb + ((64 + hi * 16) ^ rxor)]); \
            }                                                                    \
            XNr = (f32x4){0.f, 0.f, 0.f, 0.f};                                   \
            XNz = (f32x4){0.f, 0.f, 0.f, 0.f};                                   \
            XNx = (f32x4){bnx, bnx, bnx, bnx};                                   \
            XNr = __builtin_amdgcn_mfma_f32_16x16x32_f16(Axn0, Bf[0][4], XNr, 0, 0, 0); \
            XNz = __builtin_amdgcn_mfma_f32_16x16x32_f16(Axn0, Bf[1][4], XNz, 0, 0, 0); \
            XNx = __builtin_amdgcn_mfma_f32_16x16x32_f16(Axn0, Bf[2][4], XNx, 0, 0, 0); \
            XNr = __builtin_amdgcn_mfma_f32_16x16x32_f16(Axn1, Bf[0][5], XNr, 0, 0, 0); \
            XNz = __builtin_amdgcn_mfma_f32_16x16x32_f16(Axn1, Bf[1][5], XNz, 0, 0, 0); \
            XNx = __builtin_amdgcn_mfma_f32_16x16x32_f16(Axn1, Bf[2][5], XNx, 0, 0, 0); \
        }                                                                        \
        if (t_ > 0) { OUTSTEP(t_ - 1) }                                          \
        __builtin_amdgcn_sched_barrier(0);  /* pin shadow work pre-barrier */    \
        __syncthreads();                                                         \
        if (!(lo & 3)) {                                                         \
            _Pragma("unroll") for (int ks = 0; ks < 4; ++ks)                     \
                A[ks] = *(const half8*)(&hsm[WP][rb + ((ks * 64 + hi * 16) ^ rxor)]); \
        }                                                                        \
    }

    for (int t = 0; t < Tt; t += 2) {
        GSTEP(t,     0, axrA, axzA, axxA, axrB, axzB, axxB)
        GSTEP(t + 1, 1, axrB, axzB, axxB, axrA, axzA, axxA)
    }

    // Epilogue: final row T-1 (A[ks] holds latents[T-1] after the last barrier).
    latp[(size_t)(Tt - 1) * 128] = hprev;
    OUTSTEP(Tt - 1)
#undef GSTEP
#undef OUTSTEP
}

extern "C" void kernel_launch(void* const* d_in, const int* in_sizes, int n_in,
                              void* d_out, int out_size, void* d_ws, size_t ws_size,
                              hipStream_t stream) {
    const float* inputs = (const float*)d_in[0];
    const float* W_ih   = (const float*)d_in[1];
    const float* W_hh   = (const float*)d_in[2];
    const float* b_ih   = (const float*)d_in[3];
    const float* b_hh   = (const float*)d_in[4];
    const float* W_out  = (const float*)d_in[5];
    const float* b_out  = (const float*)d_in[6];

    float* out     = (float*)d_out;
    float* latents = out + (size_t)Bb * Tt * Oo;

    // Everything fused into one kernel; d_ws unused.
    gru_mfma<<<16, 512, 0, stream>>>(W_hh, b_hh, W_ih, b_ih, W_out, b_out,
                                     inputs, out, latents);
}

// Round 16
// 924.004 us; speedup vs baseline: 1.1687x; 1.1687x over previous
//
#include <hip/hip_runtime.h>

#define Bb 64
#define Tt 2048
#define Ii 64
#define Hh 128
#define Gg 384   // 3*H
#define Oo 64

typedef _Float16 f16;
typedef _Float16 half8 __attribute__((ext_vector_type(8)));
typedef __fp16 fp16v2 __attribute__((ext_vector_type(2)));   // cvt_pkrtz native type
typedef float f32x4 __attribute__((ext_vector_type(4)));
typedef unsigned int u32;
typedef unsigned int u32x4 __attribute__((ext_vector_type(4)));

static __device__ __forceinline__ float cvt_lo(u32 u) {
    fp16v2 v = __builtin_bit_cast(fp16v2, u);
    return (float)v[0];
}
static __device__ __forceinline__ float cvt_hi(u32 u) {
    fp16v2 v = __builtin_bit_cast(fp16v2, u);
    return (float)v[1];
}

// ---------------- K1: MFMA x-projection. 2048 blocks x 256 threads, 64 rows each.
// xg[row, g] = x[row,:] @ W_ih[g,:] + b_ih[g], stored f16 in R9 layout:
// g<128 -> xR[row][g]; g in [128,256) -> xZN[row][2(g-128)] (z);
// g in [256,384) -> xZN[row][2(g-256)+1] (n).
// x-tile staged in LDS with ((row&7)<<4) XOR swizzle (2-way banks = free).
__global__ __launch_bounds__(256, 2) void xproj_mfma(
    const float* __restrict__ inputs, const float* __restrict__ W_ih,
    const float* __restrict__ b_ih, f16* __restrict__ xR, f16* __restrict__ xZN)
{
    __shared__ __align__(16) unsigned char xls[64 * 128];  // [row][2k B] f16, swz

    const int tid = threadIdx.x;
    const int w   = tid >> 6;
    const int l   = tid & 63;
    const int lo  = l & 15;
    const int hi  = l >> 4;
    const int rowBase = blockIdx.x * 64;

    // B fragments + biases: wave w covers gate-cols [w*96, w*96+96).
    half8 Bfr[6][2];
    float bias[6];
#pragma unroll
    for (int nt = 0; nt < 6; ++nt) {
        const int g = w * 96 + nt * 16 + lo;
#pragma unroll
        for (int ks = 0; ks < 2; ++ks) {
            const float* wp = W_ih + (size_t)g * 64 + ks * 32 + hi * 8;
            half8 hv;
#pragma unroll
            for (int q = 0; q < 8; ++q) hv[q] = (f16)wp[q];
            Bfr[nt][ks] = hv;
        }
        bias[nt] = b_ih[g];
    }

    // Stage x-tile: thread covers (row r = tid>>2, k c0 = (tid&3)*16), 16 f32.
    {
        const int r  = tid >> 2;
        const int c0 = (tid & 3) * 16;
        const float4* src = (const float4*)(inputs + (size_t)(rowBase + r) * 64 + c0);
        const float4 v0 = src[0], v1 = src[1], v2 = src[2], v3 = src[3];
        u32x4 d0, d1;
        d0[0] = __builtin_bit_cast(u32, __builtin_amdgcn_cvt_pkrtz(v0.x, v0.y));
        d0[1] = __builtin_bit_cast(u32, __builtin_amdgcn_cvt_pkrtz(v0.z, v0.w));
        d0[2] = __builtin_bit_cast(u32, __builtin_amdgcn_cvt_pkrtz(v1.x, v1.y));
        d0[3] = __builtin_bit_cast(u32, __builtin_amdgcn_cvt_pkrtz(v1.z, v1.w));
        d1[0] = __builtin_bit_cast(u32, __builtin_amdgcn_cvt_pkrtz(v2.x, v2.y));
        d1[1] = __builtin_bit_cast(u32, __builtin_amdgcn_cvt_pkrtz(v2.z, v2.w));
        d1[2] = __builtin_bit_cast(u32, __builtin_amdgcn_cvt_pkrtz(v3.x, v3.y));
        d1[3] = __builtin_bit_cast(u32, __builtin_amdgcn_cvt_pkrtz(v3.z, v3.w));
        const int base = r * 128;
        const int sw   = (r & 7) << 4;
        *(u32x4*)(&xls[base + ((2 * c0) ^ sw)])      = d0;
        *(u32x4*)(&xls[base + ((2 * c0 + 16) ^ sw)]) = d1;
    }
    __syncthreads();

    // A fragments: tile m rows [m*16, m*16+16), lane row = m*16+lo, k-chunk hi*8.
    half8 Af[4][2];
#pragma unroll
    for (int m = 0; m < 4; ++m)
#pragma unroll
        for (int ks = 0; ks < 2; ++ks) {
            const int row = m * 16 + lo;
            Af[m][ks] = *(const half8*)(
                &xls[row * 128 + ((ks * 64 + hi * 16) ^ ((row & 7) << 4))]);
        }

    // Compute + store. C/D: col = lo, row = hi*4 + q.
#pragma unroll
    for (int nt = 0; nt < 6; ++nt) {
        const int g    = w * 96 + nt * 16 + lo;
        const int gate = g >> 7;
        const int j    = g & 127;
#pragma unroll
        for (int m = 0; m < 4; ++m) {
            f32x4 acc = {bias[nt], bias[nt], bias[nt], bias[nt]};
            acc = __builtin_amdgcn_mfma_f32_16x16x32_f16(Af[m][0], Bfr[nt][0], acc, 0, 0, 0);
            acc = __builtin_amdgcn_mfma_f32_16x16x32_f16(Af[m][1], Bfr[nt][1], acc, 0, 0, 0);
            const int r0 = rowBase + m * 16 + hi * 4;
#pragma unroll
            for (int q = 0; q < 4; ++q) {
                const f16 val = (f16)acc[q];
                const size_t row = (size_t)(r0 + q);
                if (gate == 0)      xR[row * 128 + j] = val;
                else if (gate == 1) xZN[row * 256 + 2 * j] = val;
                else                xZN[row * 256 + 2 * j + 1] = val;
            }
        }
    }
}

// ---------------- K2: MFMA recurrence (R9 structure, measured 934 cy/step)
// + balanced fused out-proj. 16 blocks x 512 threads; 4 batches/block.
// Batch b in A-row 4b; C row 4b = (hi=b, reg 0) -> lane (hi,lo) evals its own
// (b=bb0+hi, j=jj). A-frag re-read by lanes lo in {0,4,8,12}; h ping-pong LDS
// with b-parity XOR; one __syncthreads per step; per-lane x reg-prefetch dist-2.
// Out-proj: out[t-1] computed from A[ks] (= h(t-1) frags) right after the gate
// MFMAs; even rows by waves 0-3, odd rows by waves 4-7 (balanced).
__global__ __launch_bounds__(512, 2) void gru_mfma(
    const float* __restrict__ W_hh, const float* __restrict__ b_hh,
    const f16* __restrict__ xR, const f16* __restrict__ xZN,
    const float* __restrict__ W_out, const float* __restrict__ b_out,
    float* __restrict__ latents, float* __restrict__ out)
{
    __shared__ __align__(16) unsigned char hsm[2][1024];  // [b][j] f16, b-parity XOR

    const int tid = threadIdx.x;
    const int w   = tid >> 6;
    const int l   = tid & 63;
    const int lo  = l & 15;
    const int hi  = l >> 4;
    const int jj  = w * 16 + lo;      // this lane's hidden column
    const int bb0 = blockIdx.x * 4;   // 4 batches per block

    // Gate B fragments: lane lo -> col jj, hi -> k-chunk of 8.
    half8 Bf[3][4];
#pragma unroll
    for (int gt = 0; gt < 3; ++gt)
#pragma unroll
        for (int ks = 0; ks < 4; ++ks) {
            const float* wp = W_hh + (size_t)(gt * 128 + jj) * 128 + ks * 32 + hi * 8;
            half8 hv;
#pragma unroll
            for (int q = 0; q < 8; ++q) hv[q] = (f16)wp[q];
            Bf[gt][ks] = hv;
        }
#pragma unroll
    for (int gt = 0; gt < 3; ++gt)
#pragma unroll
        for (int ks = 0; ks < 4; ++ks)
            asm volatile("" : "+v"(Bf[gt][ks]));

    // Out-proj B fragments: all waves hold W_out rows (jj & 63).
    const int oc = jj & 63;
    half8 Bw[4];
#pragma unroll
    for (int ks = 0; ks < 4; ++ks) {
        const float* wp = W_out + (size_t)oc * 128 + ks * 32 + hi * 8;
        half8 hv;
#pragma unroll
        for (int q = 0; q < 8; ++q) hv[q] = (f16)wp[q];
        Bw[ks] = hv;
    }
#pragma unroll
    for (int ks = 0; ks < 4; ++ks) asm volatile("" : "+v"(Bw[ks]));
    const float bo = b_out[oc];

    const float br = b_hh[jj];
    const float bz = b_hh[128 + jj];
    const float bn = b_hh[256 + jj];

    // Per-lane streams: this lane owns (b = bb0 + hi, j = jj).
    const f16* xrp  = xR  + (size_t)(bb0 + hi) * Tt * 128 + jj;
    const f16* xznp = xZN + (size_t)(bb0 + hi) * Tt * 256 + 2 * jj;
    float*     latp = latents + (size_t)(bb0 + hi) * Tt * 128 + jj;
    float*     outp = out     + (size_t)(bb0 + hi) * Tt * 64  + oc;

    // LDS addresses (R9-validated).
    const int waddr = hi * 256 + ((2 * jj) ^ ((hi & 1) << 6));
    const int rxor  = ((lo >> 2) & 1) << 6;
    const int rb    = (lo << 6);   // = (lo>>2)*256 for lo in {0,4,8,12}

    // 2-deep x prefetch: set A serves even t, set B serves odd t.
    f16 xrA = xrp[0];
    f16 xrB = xrp[128];
    u32 xzA = *(const u32*)xznp;
    u32 xzB = *(const u32*)(xznp + 256);

    float hreg = 0.f;
    half8 A[4];
    {
        half8 z8 = {};
#pragma unroll
        for (int ks = 0; ks < 4; ++ks) A[ks] = z8;   // rows != 4b stay zero forever
    }

// Out-proj for row TR (A[ks] = latents[TR] fragments); COND picks wave group.
#define OUTSTEP(TR, COND)                                                        \
    if (COND) {                                                                  \
        f32x4 aco0 = {bo, bo, bo, bo};                                           \
        f32x4 aco1 = {0.f, 0.f, 0.f, 0.f};                                       \
        aco0 = __builtin_amdgcn_mfma_f32_16x16x32_f16(A[0], Bw[0], aco0, 0, 0, 0); \
        aco1 = __builtin_amdgcn_mfma_f32_16x16x32_f16(A[1], Bw[1], aco1, 0, 0, 0); \
        aco0 = __builtin_amdgcn_mfma_f32_16x16x32_f16(A[2], Bw[2], aco0, 0, 0, 0); \
        aco1 = __builtin_amdgcn_mfma_f32_16x16x32_f16(A[3], Bw[3], aco1, 0, 0, 0); \
        outp[(size_t)(TR) * 64] = aco0[0] + aco1[0];                             \
    }

#define GSTEP(T, WP, XRC, XZC, OCOND)                                            \
    {                                                                            \
        const int t_ = (T);                                                      \
        const float xr_ = (float)XRC;                                            \
        const float xz_ = cvt_lo(XZC);                                           \
        const float xn_ = cvt_hi(XZC);                                           \
        if (t_ + 2 < Tt) {                                                       \
            XRC = xrp[(size_t)(t_ + 2) * 128];                                   \
            XZC = *(const u32*)(xznp + (size_t)(t_ + 2) * 256);                  \
        }                                                                        \
        f32x4 accr = {br, br, br, br};                                           \
        f32x4 accz = {bz, bz, bz, bz};                                           \
        f32x4 accn = {bn, bn, bn, bn};                                           \
        _Pragma("unroll") for (int ks = 0; ks < 4; ++ks) {                       \
            accr = __builtin_amdgcn_mfma_f32_16x16x32_f16(A[ks], Bf[0][ks], accr, 0, 0, 0); \
            accz = __builtin_amdgcn_mfma_f32_16x16x32_f16(A[ks], Bf[1][ks], accz, 0, 0, 0); \
            accn = __builtin_amdgcn_mfma_f32_16x16x32_f16(A[ks], Bf[2][ks], accn, 0, 0, 0); \
        }                                                                        \
        /* off-chain while gate MFMAs drain: out-proj of row t-1 */              \
        if (t_ > 0) { OUTSTEP(t_ - 1, OCOND) }                                   \
        /* batch bb0+hi row (=4*hi) lives in reg 0 of this lane group */         \
        const float r = __builtin_amdgcn_rcpf(1.f + __expf(-(accr[0] + xr_)));   \
        const float z = __builtin_amdgcn_rcpf(1.f + __expf(-(accz[0] + xz_)));   \
        const float a = xn_ + r * (accn[0]);                                     \
        const float n = 1.f - 2.f * __builtin_amdgcn_rcpf(__expf(2.f * a) + 1.f); \
        const float hnew = n + z * (hreg - n);                                   \
        hreg = hnew;                                                             \
        latp[(size_t)t_ * 128] = hnew;                                           \
        const float other = __shfl_xor(hnew, 1);                                 \
        if (!(l & 1)) {                                                          \
            const fp16v2 pkh = __builtin_amdgcn_cvt_pkrtz(hnew, other);          \
            *(fp16v2*)(&hsm[WP][waddr]) = pkh;                                   \
        }                                                                        \
        __syncthreads();                                                         \
        if (!(lo & 3)) {                                                         \
            _Pragma("unroll") for (int ks = 0; ks < 4; ++ks)                     \
                A[ks] = *(const half8*)(&hsm[WP][rb + ((ks * 64 + hi * 16) ^ rxor)]); \
        }                                                                        \
    }

    for (int t = 0; t < Tt; t += 2) {
        GSTEP(t,     0, xrA, xzA, (w >= 4))   // row t-1 is odd  -> waves 4-7
        GSTEP(t + 1, 1, xrB, xzB, (w < 4))    // row t   is even -> waves 0-3
    }

    // Epilogue: row Tt-1 (odd) out-proj from the final A fragments.
    OUTSTEP(Tt - 1, (w >= 4))
#undef GSTEP
#undef OUTSTEP
}

extern "C" void kernel_launch(void* const* d_in, const int* in_sizes, int n_in,
                              void* d_out, int out_size, void* d_ws, size_t ws_size,
                              hipStream_t stream) {
    const float* inputs = (const float*)d_in[0];
    const float* W_ih   = (const float*)d_in[1];
    const float* W_hh   = (const float*)d_in[2];
    const float* b_ih   = (const float*)d_in[3];
    const float* b_hh   = (const float*)d_in[4];
    const float* W_out  = (const float*)d_in[5];
    const float* b_out  = (const float*)d_in[6];

    float* out     = (float*)d_out;
    float* latents = out + (size_t)Bb * Tt * Oo;

    // x_proj staging (f16): r-gates [B][T][128]; z/n interleaved [B][T][128][2].
    const size_t xbytes = (size_t)Bb * Tt * Gg * sizeof(f16);  // 100,663,296 B
    f16 *xR, *xZN;
    if (ws_size >= xbytes) {
        xR  = (f16*)d_ws;
        xZN = xR + (size_t)Bb * Tt * Hh;
    } else {
        // Alias into d_out: xR fits exactly in the output region, xZN exactly
        // in the latents region (rows byte-aligned 1:1). K2's latents store at
        // (b,t) hits xZN row (b,t), last read at step t-2's prefetch; K2's out
        // store at (b,t-1) hits xR row (b,t-1), last read at step t-3. Both
        // strictly read-before-write per lane-column.
        xR  = (f16*)d_out;
        xZN = (f16*)latents;
    }

    xproj_mfma<<<2048, 256, 0, stream>>>(inputs, W_ih, b_ih, xR, xZN);
    gru_mfma<<<16, 512, 0, stream>>>(W_hh, b_hh, xR, xZN, W_out, b_out,
                                     latents, out);
}

// Round 18
// 865.053 us; speedup vs baseline: 1.2484x; 1.0681x over previous
//
#include <hip/hip_runtime.h>

#define Bb 64
#define Tt 2048
#define Ii 64
#define Hh 128
#define Gg 384   // 3*H
#define Oo 64

typedef _Float16 f16;
typedef _Float16 half8 __attribute__((ext_vector_type(8)));
typedef __fp16 fp16v2 __attribute__((ext_vector_type(2)));   // cvt_pkrtz native type
typedef float f32x4 __attribute__((ext_vector_type(4)));
typedef unsigned int u32;
typedef unsigned int u32x4 __attribute__((ext_vector_type(4)));

static __device__ __forceinline__ float cvt_lo(u32 u) {
    fp16v2 v = __builtin_bit_cast(fp16v2, u);
    return (float)v[0];
}
static __device__ __forceinline__ float cvt_hi(u32 u) {
    fp16v2 v = __builtin_bit_cast(fp16v2, u);
    return (float)v[1];
}

// ---------------- K1: MFMA x-projection. 2048 blocks x 256 threads, 64 rows each.
// (R16-validated, unchanged.) xg[row,g] = x[row,:]@W_ih[g,:] + b_ih[g], f16 out:
// g<128 -> xR[row][g]; [128,256) -> xZN[row][2(g-128)]; [256,384) -> xZN[..+1].
__global__ __launch_bounds__(256, 2) void xproj_mfma(
    const float* __restrict__ inputs, const float* __restrict__ W_ih,
    const float* __restrict__ b_ih, f16* __restrict__ xR, f16* __restrict__ xZN)
{
    __shared__ __align__(16) unsigned char xls[64 * 128];  // [row][2k B] f16, swz

    const int tid = threadIdx.x;
    const int w   = tid >> 6;
    const int l   = tid & 63;
    const int lo  = l & 15;
    const int hi  = l >> 4;
    const int rowBase = blockIdx.x * 64;

    // B fragments + biases: wave w covers gate-cols [w*96, w*96+96).
    half8 Bfr[6][2];
    float bias[6];
#pragma unroll
    for (int nt = 0; nt < 6; ++nt) {
        const int g = w * 96 + nt * 16 + lo;
#pragma unroll
        for (int ks = 0; ks < 2; ++ks) {
            const float* wp = W_ih + (size_t)g * 64 + ks * 32 + hi * 8;
            half8 hv;
#pragma unroll
            for (int q = 0; q < 8; ++q) hv[q] = (f16)wp[q];
            Bfr[nt][ks] = hv;
        }
        bias[nt] = b_ih[g];
    }

    // Stage x-tile: thread covers (row r = tid>>2, k c0 = (tid&3)*16), 16 f32.
    {
        const int r  = tid >> 2;
        const int c0 = (tid & 3) * 16;
        const float4* src = (const float4*)(inputs + (size_t)(rowBase + r) * 64 + c0);
        const float4 v0 = src[0], v1 = src[1], v2 = src[2], v3 = src[3];
        u32x4 d0, d1;
        d0[0] = __builtin_bit_cast(u32, __builtin_amdgcn_cvt_pkrtz(v0.x, v0.y));
        d0[1] = __builtin_bit_cast(u32, __builtin_amdgcn_cvt_pkrtz(v0.z, v0.w));
        d0[2] = __builtin_bit_cast(u32, __builtin_amdgcn_cvt_pkrtz(v1.x, v1.y));
        d0[3] = __builtin_bit_cast(u32, __builtin_amdgcn_cvt_pkrtz(v1.z, v1.w));
        d1[0] = __builtin_bit_cast(u32, __builtin_amdgcn_cvt_pkrtz(v2.x, v2.y));
        d1[1] = __builtin_bit_cast(u32, __builtin_amdgcn_cvt_pkrtz(v2.z, v2.w));
        d1[2] = __builtin_bit_cast(u32, __builtin_amdgcn_cvt_pkrtz(v3.x, v3.y));
        d1[3] = __builtin_bit_cast(u32, __builtin_amdgcn_cvt_pkrtz(v3.z, v3.w));
        const int base = r * 128;
        const int sw   = (r & 7) << 4;
        *(u32x4*)(&xls[base + ((2 * c0) ^ sw)])      = d0;
        *(u32x4*)(&xls[base + ((2 * c0 + 16) ^ sw)]) = d1;
    }
    __syncthreads();

    // A fragments: tile m rows [m*16, m*16+16), lane row = m*16+lo, k-chunk hi*8.
    half8 Af[4][2];
#pragma unroll
    for (int m = 0; m < 4; ++m)
#pragma unroll
        for (int ks = 0; ks < 2; ++ks) {
            const int row = m * 16 + lo;
            Af[m][ks] = *(const half8*)(
                &xls[row * 128 + ((ks * 64 + hi * 16) ^ ((row & 7) << 4))]);
        }

    // Compute + store. C/D: col = lo, row = hi*4 + q.
#pragma unroll
    for (int nt = 0; nt < 6; ++nt) {
        const int g    = w * 96 + nt * 16 + lo;
        const int gate = g >> 7;
        const int j    = g & 127;
#pragma unroll
        for (int m = 0; m < 4; ++m) {
            f32x4 acc = {bias[nt], bias[nt], bias[nt], bias[nt]};
            acc = __builtin_amdgcn_mfma_f32_16x16x32_f16(Af[m][0], Bfr[nt][0], acc, 0, 0, 0);
            acc = __builtin_amdgcn_mfma_f32_16x16x32_f16(Af[m][1], Bfr[nt][1], acc, 0, 0, 0);
            const int r0 = rowBase + m * 16 + hi * 4;
#pragma unroll
            for (int q = 0; q < 4; ++q) {
                const f16 val = (f16)acc[q];
                const size_t row = (size_t)(r0 + q);
                if (gate == 0)      xR[row * 128 + j] = val;
                else if (gate == 1) xZN[row * 256 + 2 * j] = val;
                else                xZN[row * 256 + 2 * j + 1] = val;
            }
        }
    }
}

// ---------------- K2: MFMA recurrence + fused out-proj (R16 structure).
// R17 micro-trims (stride bug fixed): (1) gate MFMA chains split 2+2;
// (2) direct per-lane b16 h-write (element slot jj^32 — layout-identical to
// the pack-pair scheme); (3) strength-reduced stream pointers: xr stride
// 2 steps = +256 f16, xzn = +512 f16.
__global__ __launch_bounds__(512, 2) void gru_mfma(
    const float* __restrict__ W_hh, const float* __restrict__ b_hh,
    const f16* __restrict__ xR, const f16* __restrict__ xZN,
    const float* __restrict__ W_out, const float* __restrict__ b_out,
    float* __restrict__ latents, float* __restrict__ out)
{
    __shared__ __align__(16) unsigned char hsm[2][1024];  // [b][j] f16, b-parity XOR

    const int tid = threadIdx.x;
    const int w   = tid >> 6;
    const int l   = tid & 63;
    const int lo  = l & 15;
    const int hi  = l >> 4;
    const int jj  = w * 16 + lo;      // this lane's hidden column
    const int bb0 = blockIdx.x * 4;   // 4 batches per block

    // Gate B fragments: lane lo -> col jj, hi -> k-chunk of 8.
    half8 Bf[3][4];
#pragma unroll
    for (int gt = 0; gt < 3; ++gt)
#pragma unroll
        for (int ks = 0; ks < 4; ++ks) {
            const float* wp = W_hh + (size_t)(gt * 128 + jj) * 128 + ks * 32 + hi * 8;
            half8 hv;
#pragma unroll
            for (int q = 0; q < 8; ++q) hv[q] = (f16)wp[q];
            Bf[gt][ks] = hv;
        }
#pragma unroll
    for (int gt = 0; gt < 3; ++gt)
#pragma unroll
        for (int ks = 0; ks < 4; ++ks)
            asm volatile("" : "+v"(Bf[gt][ks]));

    // Out-proj B fragments: all waves hold W_out rows (jj & 63).
    const int oc = jj & 63;
    half8 Bw[4];
#pragma unroll
    for (int ks = 0; ks < 4; ++ks) {
        const float* wp = W_out + (size_t)oc * 128 + ks * 32 + hi * 8;
        half8 hv;
#pragma unroll
        for (int q = 0; q < 8; ++q) hv[q] = (f16)wp[q];
        Bw[ks] = hv;
    }
#pragma unroll
    for (int ks = 0; ks < 4; ++ks) asm volatile("" : "+v"(Bw[ks]));
    const float bo = b_out[oc];

    const float br = b_hh[jj];
    const float bz = b_hh[128 + jj];
    const float bn = b_hh[256 + jj];

    // Strength-reduced per-lane streams for (b = bb0 + hi, j = jj).
    const f16* xrpA  = xR  + (size_t)(bb0 + hi) * Tt * 128 + jj;          // t even
    const f16* xrpB  = xrpA + 128;                                        // t odd
    const f16* xznpA = xZN + (size_t)(bb0 + hi) * Tt * 256 + 2 * jj;
    const f16* xznpB = xznpA + 256;
    float*     latp  = latents + (size_t)(bb0 + hi) * Tt * 128 + jj;
    float*     outp  = out     + (size_t)(bb0 + hi) * Tt * 64  + oc;

    // LDS addresses (R9-validated layout; write now direct per-lane b16).
    const int waddr = hi * 256 + ((2 * jj) ^ ((hi & 1) << 6));
    const int rxor  = ((lo >> 2) & 1) << 6;
    const int rb    = (lo << 6);   // = (lo>>2)*256 for lo in {0,4,8,12}

    // 2-deep x prefetch: set A serves even t, set B serves odd t.
    f16 xrA = xrpA[0];
    f16 xrB = xrpB[0];
    u32 xzA = *(const u32*)xznpA;
    u32 xzB = *(const u32*)xznpB;
    xrpA += 256; xrpB += 256;       // advance 2 steps: 2 x 128 f16
    xznpA += 512; xznpB += 512;     // advance 2 steps: 2 x 256 f16

    float hreg = 0.f;
    half8 A[4];
    {
        half8 z8 = {};
#pragma unroll
        for (int ks = 0; ks < 4; ++ks) A[ks] = z8;   // rows != 4b stay zero forever
    }

// Out-proj for row TR (A[ks] = latents[TR] fragments); COND picks wave group.
#define OUTSTEP(TR, COND)                                                        \
    if (COND) {                                                                  \
        f32x4 aco0 = {bo, bo, bo, bo};                                           \
        f32x4 aco1 = {0.f, 0.f, 0.f, 0.f};                                       \
        aco0 = __builtin_amdgcn_mfma_f32_16x16x32_f16(A[0], Bw[0], aco0, 0, 0, 0); \
        aco1 = __builtin_amdgcn_mfma_f32_16x16x32_f16(A[1], Bw[1], aco1, 0, 0, 0); \
        aco0 = __builtin_amdgcn_mfma_f32_16x16x32_f16(A[2], Bw[2], aco0, 0, 0, 0); \
        aco1 = __builtin_amdgcn_mfma_f32_16x16x32_f16(A[3], Bw[3], aco1, 0, 0, 0); \
        outp[(size_t)(TR) * 64] = aco0[0] + aco1[0];                             \
    }

#define GSTEP(T, WP, XRC, XZC, XRP, XZNP, OCOND)                                 \
    {                                                                            \
        const int t_ = (T);                                                      \
        const float xr_ = (float)XRC;                                            \
        const float xz_ = cvt_lo(XZC);                                           \
        const float xn_ = cvt_hi(XZC);                                           \
        if (t_ + 2 < Tt) {                                                       \
            XRC = XRP[0];                                                        \
            XZC = *(const u32*)XZNP;                                             \
            XRP += 256; XZNP += 512;                                             \
        }                                                                        \
        /* gate MFMAs: 2+2 split chains per gate */                              \
        f32x4 accr0 = {br, br, br, br},     accr1 = {0.f, 0.f, 0.f, 0.f};        \
        f32x4 accz0 = {bz, bz, bz, bz},     accz1 = {0.f, 0.f, 0.f, 0.f};        \
        f32x4 accn0 = {bn, bn, bn, bn},     accn1 = {0.f, 0.f, 0.f, 0.f};        \
        accr0 = __builtin_amdgcn_mfma_f32_16x16x32_f16(A[0], Bf[0][0], accr0, 0, 0, 0); \
        accz0 = __builtin_amdgcn_mfma_f32_16x16x32_f16(A[0], Bf[1][0], accz0, 0, 0, 0); \
        accn0 = __builtin_amdgcn_mfma_f32_16x16x32_f16(A[0], Bf[2][0], accn0, 0, 0, 0); \
        accr1 = __builtin_amdgcn_mfma_f32_16x16x32_f16(A[1], Bf[0][1], accr1, 0, 0, 0); \
        accz1 = __builtin_amdgcn_mfma_f32_16x16x32_f16(A[1], Bf[1][1], accz1, 0, 0, 0); \
        accn1 = __builtin_amdgcn_mfma_f32_16x16x32_f16(A[1], Bf[2][1], accn1, 0, 0, 0); \
        accr0 = __builtin_amdgcn_mfma_f32_16x16x32_f16(A[2], Bf[0][2], accr0, 0, 0, 0); \
        accz0 = __builtin_amdgcn_mfma_f32_16x16x32_f16(A[2], Bf[1][2], accz0, 0, 0, 0); \
        accn0 = __builtin_amdgcn_mfma_f32_16x16x32_f16(A[2], Bf[2][2], accn0, 0, 0, 0); \
        accr1 = __builtin_amdgcn_mfma_f32_16x16x32_f16(A[3], Bf[0][3], accr1, 0, 0, 0); \
        accz1 = __builtin_amdgcn_mfma_f32_16x16x32_f16(A[3], Bf[1][3], accz1, 0, 0, 0); \
        accn1 = __builtin_amdgcn_mfma_f32_16x16x32_f16(A[3], Bf[2][3], accn1, 0, 0, 0); \
        /* off-chain while gate chains drain: out-proj of row t-1 */             \
        if (t_ > 0) { OUTSTEP(t_ - 1, OCOND) }                                   \
        /* batch bb0+hi row (=4*hi) lives in reg 0 of this lane group */         \
        const float r = __builtin_amdgcn_rcpf(1.f + __expf(-(accr0[0] + accr1[0] + xr_))); \
        const float z = __builtin_amdgcn_rcpf(1.f + __expf(-(accz0[0] + accz1[0] + xz_))); \
        const float a = xn_ + r * (accn0[0] + accn1[0]);                         \
        const float n = 1.f - 2.f * __builtin_amdgcn_rcpf(__expf(2.f * a) + 1.f); \
        const float hnew = n + z * (hreg - n);                                   \
        hreg = hnew;                                                             \
        latp[(size_t)t_ * 128] = hnew;                                           \
        *(f16*)(&hsm[WP][waddr]) = (f16)hnew;   /* direct b16, layout-identical */ \
        __syncthreads();                                                         \
        if (!(lo & 3)) {                                                         \
            _Pragma("unroll") for (int ks = 0; ks < 4; ++ks)                     \
                A[ks] = *(const half8*)(&hsm[WP][rb + ((ks * 64 + hi * 16) ^ rxor)]); \
        }                                                                        \
    }

    for (int t = 0; t < Tt; t += 2) {
        GSTEP(t,     0, xrA, xzA, xrpA, xznpA, (w >= 4))  // row t-1 odd -> waves 4-7
        GSTEP(t + 1, 1, xrB, xzB, xrpB, xznpB, (w < 4))   // row t even -> waves 0-3
    }

    // Epilogue: row Tt-1 (odd) out-proj from the final A fragments.
    OUTSTEP(Tt - 1, (w >= 4))
#undef GSTEP
#undef OUTSTEP
}

extern "C" void kernel_launch(void* const* d_in, const int* in_sizes, int n_in,
                              void* d_out, int out_size, void* d_ws, size_t ws_size,
                              hipStream_t stream) {
    const float* inputs = (const float*)d_in[0];
    const float* W_ih   = (const float*)d_in[1];
    const float* W_hh   = (const float*)d_in[2];
    const float* b_ih   = (const float*)d_in[3];
    const float* b_hh   = (const float*)d_in[4];
    const float* W_out  = (const float*)d_in[5];
    const float* b_out  = (const float*)d_in[6];

    float* out     = (float*)d_out;
    float* latents = out + (size_t)Bb * Tt * Oo;

    // x_proj staging (f16): r-gates [B][T][128]; z/n interleaved [B][T][128][2].
    const size_t xbytes = (size_t)Bb * Tt * Gg * sizeof(f16);  // 100,663,296 B
    f16 *xR, *xZN;
    if (ws_size >= xbytes) {
        xR  = (f16*)d_ws;
        xZN = xR + (size_t)Bb * Tt * Hh;
    } else {
        // Alias into d_out: xR fits exactly in the output region, xZN exactly
        // in the latents region (rows byte-aligned 1:1). K2's latents store at
        // (b,t) hits xZN row (b,t), last read at step t-2's prefetch; K2's out
        // store at (b,t-1) hits xR row (b,t-1), last read at step t-3. Both
        // strictly read-before-write per lane-column.
        xR  = (f16*)d_out;
        xZN = (f16*)latents;
    }

    xproj_mfma<<<2048, 256, 0, stream>>>(inputs, W_ih, b_ih, xR, xZN);
    gru_mfma<<<16, 512, 0, stream>>>(W_hh, b_hh, xR, xZN, W_out, b_out,
                                     latents, out);
}